// Round 3
// baseline (1493.787 us; speedup 1.0000x reference)
//
#include <hip/hip_runtime.h>
#include <hip/hip_bf16.h>

#define NF 22   // node features
#define H 32    // hidden dim

// ---- degree / normalization ----
__global__ void deg_init(int* __restrict__ deg, int N) {
    int i = blockIdx.x * blockDim.x + threadIdx.x;
    if (i < N) deg[i] = 1;  // self-loop
}

__global__ void deg_scatter(const int* __restrict__ dst, int* __restrict__ deg, int E) {
    int e = blockIdx.x * blockDim.x + threadIdx.x;
    if (e < E) atomicAdd(&deg[dst[e]], 1);
}

__global__ void deg_to_dis(float* __restrict__ dis, int N) {
    int i = blockIdx.x * blockDim.x + threadIdx.x;
    if (i < N) {
        int d = ((const int*)dis)[i];
        dis[i] = rsqrtf((float)d);
    }
}

// ---- h0 = x@We + be ; g1 = dis * (h0@W1) ; acc := g1 (self-loop init) ----
__global__ __launch_bounds__(256) void embed_g1(
    const float* __restrict__ x, const float* __restrict__ We,
    const float* __restrict__ be, const float* __restrict__ W1,
    const float* __restrict__ dis, float* __restrict__ h0,
    float* __restrict__ g, float* __restrict__ acc, int N)
{
    __shared__ float sWe[NF * H];
    __shared__ float sW1[H * H];
    __shared__ float sbe[H];
    __shared__ float sx[8][NF];
    __shared__ float sh[8][H];

    int tid = threadIdx.x;
    for (int j = tid; j < NF * H; j += 256) sWe[j] = We[j];
    for (int j = tid; j < H * H; j += 256) sW1[j] = W1[j];
    if (tid < H) sbe[tid] = be[tid];

    int grp = tid >> 5, t = tid & 31;
    int node = blockIdx.x * 8 + grp;
    int nodec = node < N ? node : N - 1;
    if (t < NF) sx[grp][t] = x[(size_t)nodec * NF + t];
    __syncthreads();   // covers sWe, sW1, sbe, sx

    float h = sbe[t];
#pragma unroll
    for (int k = 0; k < NF; k++) h += sx[grp][k] * sWe[k * H + t];
    sh[grp][t] = h;
    __syncthreads();   // covers sh

    float gv = 0.f;
#pragma unroll
    for (int k = 0; k < H; k++) gv += sh[grp][k] * sW1[k * H + t];
    gv *= dis[nodec];

    if (node < N) {
        size_t o = (size_t)node * H + t;
        h0[o] = h;
        g[o] = gv;
        acc[o] = gv;
    }
}

// ---- edge scatter: acc[dst] += g[src], 8 threads/edge, 4 cols each ----
__global__ __launch_bounds__(256) void scatter32(
    const int* __restrict__ src, const int* __restrict__ dst,
    const float* __restrict__ g, float* __restrict__ acc, int E)
{
    int tid = blockIdx.x * blockDim.x + threadIdx.x;
    int e = tid >> 3;
    if (e >= E) return;
    int c = (tid & 7) << 2;
    int s = src[e], d = dst[e];
    const float4 gv = *(const float4*)(g + (size_t)s * H + c);
    float* ap = acc + (size_t)d * H + c;
    atomicAdd(ap + 0, gv.x);
    atomicAdd(ap + 1, gv.y);
    atomicAdd(ap + 2, gv.z);
    atomicAdd(ap + 3, gv.w);
}

// ---- r1 = relu(dis*acc + b1); g2 = dis * ([r1,h0]@W2); acc := g2 ----
__global__ __launch_bounds__(256) void mid_g2(
    const float* __restrict__ W2, const float* __restrict__ b1,
    const float* __restrict__ dis, const float* __restrict__ h0,
    float* __restrict__ g, float* __restrict__ acc, int N)
{
    __shared__ float sW2[2 * H * H];
    __shared__ float sb1[H];
    __shared__ float srow[8][2 * H];

    int tid = threadIdx.x;
    for (int j = tid; j < 2 * H * H; j += 256) sW2[j] = W2[j];
    if (tid < H) sb1[tid] = b1[tid];
    __syncthreads();   // sb1/sW2 visible to all threads before use

    int grp = tid >> 5, t = tid & 31;
    int node = blockIdx.x * 8 + grp;
    int nodec = node < N ? node : N - 1;
    size_t o = (size_t)nodec * H + t;

    float di = dis[nodec];
    float a = acc[o];
    float r = fmaxf(di * a + sb1[t], 0.f);
    srow[grp][t] = r;
    srow[grp][H + t] = h0[o];
    __syncthreads();   // covers srow

    float gv = 0.f;
#pragma unroll
    for (int k = 0; k < 2 * H; k++) gv += srow[grp][k] * sW2[k * H + t];
    gv *= di;

    if (node < N) {
        size_t oo = (size_t)node * H + t;
        g[oo] = gv;
        acc[oo] = gv;
    }
}

// ---- final: out = relu([relu(dis*acc+b2), h0] @ Wp + bp + x[:,1]) ----
__global__ __launch_bounds__(256) void final_pred(
    const float* __restrict__ acc, const float* __restrict__ h0,
    const float* __restrict__ dis, const float* __restrict__ b2,
    const float* __restrict__ Wp, const float* __restrict__ bp,
    const float* __restrict__ x, float* __restrict__ out, int N)
{
    int i = blockIdx.x * blockDim.x + threadIdx.x;
    if (i >= N) return;
    float di = dis[i];
    float a = bp[0] + x[(size_t)i * NF + 1];
    size_t o = (size_t)i * H;
#pragma unroll
    for (int c = 0; c < H; c++)
        a += fmaxf(di * acc[o + c] + b2[c], 0.f) * Wp[c];
#pragma unroll
    for (int c = 0; c < H; c++)
        a += h0[o + c] * Wp[H + c];
    out[i] = fmaxf(a, 0.f);
}

extern "C" void kernel_launch(void* const* d_in, const int* in_sizes, int n_in,
                              void* d_out, int out_size, void* d_ws, size_t ws_size,
                              hipStream_t stream) {
    // Reference dtypes: all float tensors are float32; edge_index -> int32.
    const float* x  = (const float*)d_in[0];
    const int*   ei = (const int*)d_in[1];
    const float* We = (const float*)d_in[2];
    const float* be = (const float*)d_in[3];
    const float* W1 = (const float*)d_in[4];
    const float* b1 = (const float*)d_in[5];
    const float* W2 = (const float*)d_in[6];
    const float* b2 = (const float*)d_in[7];
    const float* Wp = (const float*)d_in[8];
    const float* bp = (const float*)d_in[9];
    float* out = (float*)d_out;

    const int N = in_sizes[0] / NF;
    const int E = in_sizes[1] / 2;
    const int* src = ei;
    const int* dst = ei + E;

    float* ws = (float*)d_ws;
    size_t Np = ((size_t)N + 127) & ~(size_t)127;
    float* dis = ws;               // N floats (aliased as int deg first)
    float* h0  = ws + Np;          // N*32
    float* g   = h0 + (size_t)N * H;   // N*32
    float* acc = g  + (size_t)N * H;   // N*32

    deg_init<<<(N + 255) / 256, 256, 0, stream>>>((int*)dis, N);
    deg_scatter<<<(E + 255) / 256, 256, 0, stream>>>(dst, (int*)dis, E);
    deg_to_dis<<<(N + 255) / 256, 256, 0, stream>>>(dis, N);

    embed_g1<<<(N + 7) / 8, 256, 0, stream>>>(x, We, be, W1, dis, h0, g, acc, N);
    scatter32<<<((size_t)E * 8 + 255) / 256, 256, 0, stream>>>(src, dst, g, acc, E);
    mid_g2<<<(N + 7) / 8, 256, 0, stream>>>(W2, b1, dis, h0, g, acc, N);
    scatter32<<<((size_t)E * 8 + 255) / 256, 256, 0, stream>>>(src, dst, g, acc, E);
    final_pred<<<(N + 255) / 256, 256, 0, stream>>>(acc, h0, dis, b2, Wp, bp, x, out, N);
}

// Round 4
// 430.006 us; speedup vs baseline: 3.4739x; 3.4739x over previous
//
#include <hip/hip_runtime.h>
#include <hip/hip_bf16.h>

#define NF 22   // node features
#define H 32    // hidden dim
#define SCAN_TILE 1024

// ---------------- counting-sort-by-dst (CSR build) ----------------

__global__ void zero_ints(int* __restrict__ p, int n) {
    int i = blockIdx.x * blockDim.x + threadIdx.x;
    if (i < n) p[i] = 0;
}

__global__ void hist_dst(const int* __restrict__ dst, int* __restrict__ cnt, int E) {
    int e = blockIdx.x * blockDim.x + threadIdx.x;
    if (e < E) atomicAdd(&cnt[dst[e]], 1);
}

// exclusive scan within tiles of 1024 (256 thr x 4 items); per-tile totals to bsum.
__global__ __launch_bounds__(256) void scan_partial(const int* __restrict__ in,
        int* __restrict__ excl, int* __restrict__ bsum, int N) {
    __shared__ int s[256];
    int b = blockIdx.x, tid = threadIdx.x;
    int idx0 = b * SCAN_TILE + tid * 4;
    int v0 = (idx0 + 0 < N) ? in[idx0 + 0] : 0;
    int v1 = (idx0 + 1 < N) ? in[idx0 + 1] : 0;
    int v2 = (idx0 + 2 < N) ? in[idx0 + 2] : 0;
    int v3 = (idx0 + 3 < N) ? in[idx0 + 3] : 0;
    s[tid] = v0 + v1 + v2 + v3;
    __syncthreads();
    for (int off = 1; off < 256; off <<= 1) {
        int t = (tid >= off) ? s[tid - off] : 0;
        __syncthreads();
        s[tid] += t;
        __syncthreads();
    }
    int run = (tid > 0) ? s[tid - 1] : 0;
    if (bsum && tid == 255) bsum[b] = s[255];
    if (idx0 + 0 < N) excl[idx0 + 0] = run; run += v0;
    if (idx0 + 1 < N) excl[idx0 + 1] = run; run += v1;
    if (idx0 + 2 < N) excl[idx0 + 2] = run; run += v2;
    if (idx0 + 3 < N) excl[idx0 + 3] = run;
}

// rowptr/cursor = excl + tile offset; dis = rsqrt(cnt+1) (self-loop degree)
__global__ void csr_finalize(const int* __restrict__ excl, const int* __restrict__ bsumExcl,
        const int* __restrict__ cnt, int* __restrict__ rowptr, int* __restrict__ cursor,
        float* __restrict__ dis, int N) {
    int i = blockIdx.x * blockDim.x + threadIdx.x;
    if (i < N) {
        int r = excl[i] + bsumExcl[i >> 10];
        rowptr[i] = r;
        cursor[i] = r;
        dis[i] = rsqrtf((float)(cnt[i] + 1));
    }
}

__global__ void permute_edges(const int* __restrict__ src, const int* __restrict__ dst,
        int* __restrict__ cursor, int* __restrict__ sorted_src, int E) {
    int e = blockIdx.x * blockDim.x + threadIdx.x;
    if (e < E) {
        int p = atomicAdd(&cursor[dst[e]], 1);
        sorted_src[p] = src[e];
    }
}

// ---------------- dense node kernels ----------------

// h0 = x@We + be ; g1 = dis * (h0@W1)
__global__ __launch_bounds__(256) void embed_g1(
    const float* __restrict__ x, const float* __restrict__ We,
    const float* __restrict__ be, const float* __restrict__ W1,
    const float* __restrict__ dis, float* __restrict__ h0,
    float* __restrict__ g, int N)
{
    __shared__ float sWe[NF * H];
    __shared__ float sW1[H * H];
    __shared__ float sbe[H];
    __shared__ float sx[8][NF];
    __shared__ float sh[8][H];

    int tid = threadIdx.x;
    for (int j = tid; j < NF * H; j += 256) sWe[j] = We[j];
    for (int j = tid; j < H * H; j += 256) sW1[j] = W1[j];
    if (tid < H) sbe[tid] = be[tid];

    int grp = tid >> 5, t = tid & 31;
    int node = blockIdx.x * 8 + grp;
    int nodec = node < N ? node : N - 1;
    if (t < NF) sx[grp][t] = x[(size_t)nodec * NF + t];
    __syncthreads();

    float h = sbe[t];
#pragma unroll
    for (int k = 0; k < NF; k++) h += sx[grp][k] * sWe[k * H + t];
    sh[grp][t] = h;
    __syncthreads();

    float gv = 0.f;
#pragma unroll
    for (int k = 0; k < H; k++) gv += sh[grp][k] * sW1[k * H + t];
    gv *= dis[nodec];

    if (node < N) {
        size_t o = (size_t)node * H + t;
        h0[o] = h;
        g[o] = gv;
    }
}

// ---- atomic-free aggregation: acc[d] = g[d] + sum_{s in N(d)} g[s] ----
// 32 lanes per node, lane = column; 2-way unrolled segment loop.
__global__ __launch_bounds__(256) void gather_agg(
    const int* __restrict__ rowptr, const int* __restrict__ cnt,
    const int* __restrict__ sorted_src,
    const float* __restrict__ g, float* __restrict__ acc, int N)
{
    int gid = blockIdx.x * blockDim.x + threadIdx.x;
    int node = gid >> 5;
    if (node >= N) return;
    int c = gid & 31;
    int start = rowptr[node];
    int end = start + cnt[node];
    float a = g[(size_t)node * H + c];  // self-loop term
    int i = start;
    for (; i + 1 < end; i += 2) {
        int s0 = sorted_src[i];
        int s1 = sorted_src[i + 1];
        a += g[(size_t)s0 * H + c];
        a += g[(size_t)s1 * H + c];
    }
    if (i < end) a += g[(size_t)sorted_src[i] * H + c];
    acc[(size_t)node * H + c] = a;
}

// r1 = relu(dis*acc + b1); g2 = dis * ([r1,h0]@W2)
__global__ __launch_bounds__(256) void mid_g2(
    const float* __restrict__ W2, const float* __restrict__ b1,
    const float* __restrict__ dis, const float* __restrict__ h0,
    float* __restrict__ g, const float* __restrict__ acc, int N)
{
    __shared__ float sW2[2 * H * H];
    __shared__ float sb1[H];
    __shared__ float srow[8][2 * H];

    int tid = threadIdx.x;
    for (int j = tid; j < 2 * H * H; j += 256) sW2[j] = W2[j];
    if (tid < H) sb1[tid] = b1[tid];
    __syncthreads();

    int grp = tid >> 5, t = tid & 31;
    int node = blockIdx.x * 8 + grp;
    int nodec = node < N ? node : N - 1;
    size_t o = (size_t)nodec * H + t;

    float di = dis[nodec];
    float r = fmaxf(di * acc[o] + sb1[t], 0.f);
    srow[grp][t] = r;
    srow[grp][H + t] = h0[o];
    __syncthreads();

    float gv = 0.f;
#pragma unroll
    for (int k = 0; k < 2 * H; k++) gv += srow[grp][k] * sW2[k * H + t];
    gv *= di;

    if (node < N) g[(size_t)node * H + t] = gv;
}

// out = relu([relu(dis*acc+b2), h0] @ Wp + bp + x[:,1])
__global__ __launch_bounds__(256) void final_pred(
    const float* __restrict__ acc, const float* __restrict__ h0,
    const float* __restrict__ dis, const float* __restrict__ b2,
    const float* __restrict__ Wp, const float* __restrict__ bp,
    const float* __restrict__ x, float* __restrict__ out, int N)
{
    int i = blockIdx.x * blockDim.x + threadIdx.x;
    if (i >= N) return;
    float di = dis[i];
    float a = bp[0] + x[(size_t)i * NF + 1];
    size_t o = (size_t)i * H;
#pragma unroll
    for (int c = 0; c < H; c++)
        a += fmaxf(di * acc[o + c] + b2[c], 0.f) * Wp[c];
#pragma unroll
    for (int c = 0; c < H; c++)
        a += h0[o + c] * Wp[H + c];
    out[i] = fmaxf(a, 0.f);
}

extern "C" void kernel_launch(void* const* d_in, const int* in_sizes, int n_in,
                              void* d_out, int out_size, void* d_ws, size_t ws_size,
                              hipStream_t stream) {
    const float* x  = (const float*)d_in[0];
    const int*   ei = (const int*)d_in[1];
    const float* We = (const float*)d_in[2];
    const float* be = (const float*)d_in[3];
    const float* W1 = (const float*)d_in[4];
    const float* b1 = (const float*)d_in[5];
    const float* W2 = (const float*)d_in[6];
    const float* b2 = (const float*)d_in[7];
    const float* Wp = (const float*)d_in[8];
    const float* bp = (const float*)d_in[9];
    float* out = (float*)d_out;

    const int N = in_sizes[0] / NF;
    const int E = in_sizes[1] / 2;
    const int* src = ei;
    const int* dst = ei + E;

    // workspace layout, all segments padded to 128 elements
    size_t Np = ((size_t)N + 127) & ~(size_t)127;
    size_t NHp = ((size_t)N * H + 127) & ~(size_t)127;
    size_t Ep = ((size_t)E + 127) & ~(size_t)127;
    float* ws = (float*)d_ws;
    float* dis  = ws;                    // Np
    float* h0   = dis + Np;              // NHp
    float* g    = h0 + NHp;              // NHp
    float* acc  = g + NHp;               // NHp
    int* cnt        = (int*)(acc + NHp); // Np
    int* excl       = cnt + Np;          // Np
    int* rowptr     = excl + Np;         // Np
    int* cursor     = rowptr + Np;       // Np
    int* sorted_src = cursor + Np;       // Ep
    int* bsum       = sorted_src + Ep;   // 1024
    int* bsumExcl   = bsum + 1024;       // 1024

    const int nb = (N + SCAN_TILE - 1) / SCAN_TILE;  // scan tiles (98)

    zero_ints<<<(N + 255) / 256, 256, 0, stream>>>(cnt, N);
    hist_dst<<<(E + 255) / 256, 256, 0, stream>>>(dst, cnt, E);
    scan_partial<<<nb, 256, 0, stream>>>(cnt, excl, bsum, N);
    scan_partial<<<1, 256, 0, stream>>>(bsum, bsumExcl, nullptr, nb);
    csr_finalize<<<(N + 255) / 256, 256, 0, stream>>>(excl, bsumExcl, cnt, rowptr, cursor, dis, N);
    permute_edges<<<(E + 255) / 256, 256, 0, stream>>>(src, dst, cursor, sorted_src, E);

    embed_g1<<<(N + 7) / 8, 256, 0, stream>>>(x, We, be, W1, dis, h0, g, N);
    gather_agg<<<((size_t)N * 32 + 255) / 256, 256, 0, stream>>>(rowptr, cnt, sorted_src, g, acc, N);
    mid_g2<<<(N + 7) / 8, 256, 0, stream>>>(W2, b1, dis, h0, g, acc, N);
    gather_agg<<<((size_t)N * 32 + 255) / 256, 256, 0, stream>>>(rowptr, cnt, sorted_src, g, acc, N);
    final_pred<<<(N + 255) / 256, 256, 0, stream>>>(acc, h0, dis, b2, Wp, bp, x, out, N);
}